// Round 7
// baseline (371.042 us; speedup 1.0000x reference)
//
#include <hip/hip_runtime.h>
#include <math.h>

#define NA 100000
#define NB 100000
#define DIM 128
#define NEDGE 1600000
#define ALPHA 0.1f
#define BCAP 32        // 128B-aligned bucket rows; P(Poisson(16) > 32) ~ 1.5e-4 -> ~25 overflow edges, handled exactly
#define OVF_CAP 65536

// ---- workspace layout (bytes, all 64-aligned); total 40,157,120 (< 40,432,832 proven OK in R2) ----
#define WS_NEBF   0          // 25,600,000  bf16 new_emb[NB*DIM]
#define WS_WBF    25600000   //     32,768  bf16 W[DIM*DIM]
#define WS_SA     25632768   //    400,000  float s_a[NA]
#define WS_SB     26032768   //    400,000  float s_b[NB]
#define WS_CNT    26432768   //    400,000  int cnt[NA] (cursor; counts ALL edges of row)
#define WS_FLAG   26832768   //         64  int flags[16]: [0]=int64-layout, [1]=overflow counter
#define WS_OVF    26832832   //    524,288  int2 ovf[OVF_CAP] = (src,dst)
#define WS_PAIRS  27357120   // 12,800,000  int bucket[NA*BCAP]  (end 40,157,120)

// fused-grid partitions: longest blocks first, shortest last (tail smoothing).
// Each partition keeps its proven standalone TLP shape (R3 lesson: never starve
// an atomic pass's wave count; R4 lesson: 1 edge/thread for atomic passes).
#define NEWEMB_BLOCKS 782    // ceil(ceil(NB/32)/4)
#define SCAT_BLOCKS   6250   // NEDGE/256, 1 edge/thread
#define SA_BLOCKS     25000  // NA/4

using bf16x8 = __attribute__((ext_vector_type(8))) short;
using f32x16 = __attribute__((ext_vector_type(16))) float;

__device__ inline short f2bf(float f) {   // RNE float->bf16
    union { float f; unsigned u; } v; v.f = f;
    const unsigned r = (v.u + 0x7FFFu + ((v.u >> 16) & 1u)) >> 16;
    return (short)r;
}

// block 0: edge-layout detect (int64 high words all zero?); blocks 1..64: W -> bf16
__global__ void k_prep(const int* __restrict__ edges32, int* __restrict__ flags,
                       const float* __restrict__ W, short* __restrict__ wbf) {
    if (blockIdx.x == 0) {
        __shared__ int any;
        if (threadIdx.x == 0) any = 0;
        __syncthreads();
        if (edges32[2 * threadIdx.x + 1] != 0) atomicOr(&any, 1);
        __syncthreads();
        if (threadIdx.x == 0) flags[0] = (any == 0) ? 1 : 0;
    } else {
        const int i = (blockIdx.x - 1) * 256 + threadIdx.x;
        if (i < DIM * DIM) wbf[i] = f2bf(W[i]);
    }
}

// Fused: newemb (MFMA) + edge scatter (atomic latency) + s_a (BW) co-resident.
// Scatter's 112us of near-idle VALU/MFMA time absorbs the other two passes.
__global__ __launch_bounds__(256) void k_fused(
    const float* __restrict__ fb, const short* __restrict__ wbf,
    const float* __restrict__ bias, const float* __restrict__ avec,
    short* __restrict__ nebf, float* __restrict__ s_b,
    const void* __restrict__ edges, const int* __restrict__ flags,
    int* __restrict__ cnt, int* __restrict__ bucket,
    int2* __restrict__ ovf, int* __restrict__ ovfcnt,
    const float* __restrict__ fa, float* __restrict__ s_a)
{
    const int lane = threadIdx.x & 63;
    if (blockIdx.x < NEWEMB_BLOCKS) {
        // ---- new_emb(bf16) = fb @ W^T + b ; s_b = new_emb @ a_bot (proven R2 kernel) ----
        const int wv = threadIdx.x >> 6;
        const int tile = blockIdx.x * 4 + wv;
        const int row0 = tile * 32;
        if (row0 >= NB) return;
        const int l31 = lane & 31;
        const int h = lane >> 5;

        f32x16 acc[4];
        #pragma unroll
        for (int nt = 0; nt < 4; ++nt)
            #pragma unroll
            for (int r = 0; r < 16; ++r) acc[nt][r] = 0.f;

        const float* arow = fb + (size_t)(row0 + l31) * DIM;   // A: m = lane&31

        #pragma unroll 2
        for (int s = 0; s < 8; ++s) {
            const int k0 = s * 16 + h * 8;                     // A/B: k = 8*(lane>>5)+j
            const float4 a0 = *(const float4*)(arow + k0);
            const float4 a1 = *(const float4*)(arow + k0 + 4);
            bf16x8 af;
            af[0] = f2bf(a0.x); af[1] = f2bf(a0.y); af[2] = f2bf(a0.z); af[3] = f2bf(a0.w);
            af[4] = f2bf(a1.x); af[5] = f2bf(a1.y); af[6] = f2bf(a1.z); af[7] = f2bf(a1.w);
            #pragma unroll
            for (int nt = 0; nt < 4; ++nt) {
                const int n = nt * 32 + l31;                   // B[k][n] = W[n][k]
                const bf16x8 bf = *(const bf16x8*)(wbf + n * DIM + k0);
                acc[nt] = __builtin_amdgcn_mfma_f32_32x32x16_bf16(af, bf, acc[nt], 0, 0, 0);
            }
        }

        float ab[4], bs[4];
        #pragma unroll
        for (int nt = 0; nt < 4; ++nt) {
            ab[nt] = avec[DIM + nt * 32 + l31];   // a_bot
            bs[nt] = bias[nt * 32 + l31];
        }
        float sb[16];
        #pragma unroll
        for (int r = 0; r < 16; ++r) {
            const int row = row0 + (r & 3) + 8 * (r >> 2) + 4 * h;  // C/D row map
            float p = 0.f;
            #pragma unroll
            for (int nt = 0; nt < 4; ++nt) {
                const float v = acc[nt][r] + bs[nt];
                nebf[(size_t)row * DIM + nt * 32 + l31] = f2bf(v);
                p += v * ab[nt];
            }
            #pragma unroll
            for (int m = 16; m; m >>= 1) p += __shfl_xor(p, m, 64);  // reduce over lane&31
            sb[r] = p;
        }
        if (l31 == 0) {
            #pragma unroll
            for (int r = 0; r < 16; ++r)
                s_b[row0 + (r & 3) + 8 * (r >> 2) + 4 * h] = sb[r];
        }
    } else if (blockIdx.x < NEWEMB_BLOCKS + SCAT_BLOCKS) {
        // ---- edge scatter: route dst into padded bucket of src; overflow exact ----
        const int e = (blockIdx.x - NEWEMB_BLOCKS) * 256 + threadIdx.x;
        if (e >= NEDGE) return;
        int src, dst;
        if (flags[0]) {
            const int4 v = ((const int4*)edges)[e];   // one int4 per int64 edge pair
            src = v.x; dst = v.z;
        } else {
            const int2 v = ((const int2*)edges)[e];
            src = v.x; dst = v.y;
        }
        const int pos = atomicAdd(&cnt[src], 1);
        if (pos < BCAP) {
            bucket[(src << 5) + pos] = dst;           // BCAP=32: 128B-aligned rows
        } else {
            const int o = atomicAdd(ovfcnt, 1);
            if (o < OVF_CAP) ovf[o] = make_int2(src, dst);
        }
    } else {
        // ---- s_a = feature_a @ a_top : one wave per row ----
        const int row = (blockIdx.x - NEWEMB_BLOCKS - SCAT_BLOCKS) * 4 + (threadIdx.x >> 6);
        if (row >= NA) return;
        const float2 v = *(const float2*)(fa + (size_t)row * DIM + 2 * lane);
        const float2 a = *(const float2*)(avec + 2 * lane);
        float p = v.x * a.x + v.y * a.y;
        #pragma unroll
        for (int m = 32; m; m >>= 1) p += __shfl_xor(p, m, 64);
        if (lane == 0) s_a[row] = p;
    }
}

// one wave per src row, quarter-wave per edge: 16 lanes x uint4 = full 256B bf16 row.
// 4-deep MLP (16 gathers in flight per wave) to probe latency- vs BW-bound regime.
#define ACC8(u, wt)                                                             \
    a0 += (wt) * __uint_as_float((u).x << 16);                                  \
    a1 += (wt) * __uint_as_float((u).x & 0xFFFF0000u);                          \
    a2 += (wt) * __uint_as_float((u).y << 16);                                  \
    a3 += (wt) * __uint_as_float((u).y & 0xFFFF0000u);                          \
    a4 += (wt) * __uint_as_float((u).z << 16);                                  \
    a5 += (wt) * __uint_as_float((u).z & 0xFFFF0000u);                          \
    a6 += (wt) * __uint_as_float((u).w << 16);                                  \
    a7 += (wt) * __uint_as_float((u).w & 0xFFFF0000u);

__device__ inline float edge_w(float sar, float sb) {
    const float sc = sar + sb;
    const float el = (sc > 0.f) ? sc : ALPHA * expm1f(sc);
    return expf(el);
}

__global__ __launch_bounds__(256) void k_rowagg(
    const int* __restrict__ cnt, const int* __restrict__ bucket_all,
    const float* __restrict__ s_a, const float* __restrict__ s_b,
    const unsigned* __restrict__ nebf, const int2* __restrict__ ovf,
    const int* __restrict__ flags, float* __restrict__ out)
{
    const int row = blockIdx.x * 4 + (threadIdx.x >> 6);
    if (row >= NA) return;
    const int lane = threadIdx.x & 63;
    const int l = lane & 15;       // channel group: bf16 elements 8l..8l+7
    const int q = lane >> 4;       // edge phase 0..3
    const int c = cnt[row];
    const int cb = (c > BCAP) ? BCAP : c;
    const int* bucket = bucket_all + (row << 5);
    const float sar = s_a[row];

    float a0 = 0.f, a1 = 0.f, a2 = 0.f, a3 = 0.f;
    float a4 = 0.f, a5 = 0.f, a6 = 0.f, a7 = 0.f, wsum = 0.f;
    int i = q;
    for (; i + 12 < cb; i += 16) {               // 4 edges per quarter per trip
        const int d0 = bucket[i];
        const int d1 = bucket[i + 4];
        const int d2 = bucket[i + 8];
        const int d3 = bucket[i + 12];
        const uint4 u0 = *(const uint4*)(nebf + (size_t)d0 * (DIM / 2) + 4 * l);
        const uint4 u1 = *(const uint4*)(nebf + (size_t)d1 * (DIM / 2) + 4 * l);
        const uint4 u2 = *(const uint4*)(nebf + (size_t)d2 * (DIM / 2) + 4 * l);
        const uint4 u3 = *(const uint4*)(nebf + (size_t)d3 * (DIM / 2) + 4 * l);
        const float w0 = edge_w(sar, s_b[d0]);
        const float w1 = edge_w(sar, s_b[d1]);
        const float w2 = edge_w(sar, s_b[d2]);
        const float w3 = edge_w(sar, s_b[d3]);
        ACC8(u0, w0)
        ACC8(u1, w1)
        ACC8(u2, w2)
        ACC8(u3, w3)
        wsum += (w0 + w1) + (w2 + w3);
    }
    for (; i + 4 < cb; i += 8) {                 // 2 edges per quarter per trip
        const int d0 = bucket[i];
        const int d1 = bucket[i + 4];
        const uint4 u0 = *(const uint4*)(nebf + (size_t)d0 * (DIM / 2) + 4 * l);
        const uint4 u1 = *(const uint4*)(nebf + (size_t)d1 * (DIM / 2) + 4 * l);
        const float w0 = edge_w(sar, s_b[d0]);
        const float w1 = edge_w(sar, s_b[d1]);
        ACC8(u0, w0)
        ACC8(u1, w1)
        wsum += w0 + w1;
    }
    for (; i < cb; i += 4) {
        const int d = bucket[i];
        const uint4 u = *(const uint4*)(nebf + (size_t)d * (DIM / 2) + 4 * l);
        const float wv = edge_w(sar, s_b[d]);
        ACC8(u, wv)
        wsum += wv;
    }
    // exact overflow fold-in (expected ~25 entries total; wave-uniform broadcast reads)
    int novf = flags[1];
    novf = (novf > OVF_CAP) ? OVF_CAP : novf;
    for (int j = q; j < novf; j += 4) {
        const int2 pe = ovf[j];
        if (pe.x == row) {
            const uint4 u = *(const uint4*)(nebf + (size_t)pe.y * (DIM / 2) + 4 * l);
            const float wv = edge_w(sar, s_b[pe.y]);
            ACC8(u, wv)
            wsum += wv;
        }
    }
    // reduce across the 4 quarter-waves (lanes l, l+16, l+32, l+48)
    a0 += __shfl_xor(a0, 16, 64); a0 += __shfl_xor(a0, 32, 64);
    a1 += __shfl_xor(a1, 16, 64); a1 += __shfl_xor(a1, 32, 64);
    a2 += __shfl_xor(a2, 16, 64); a2 += __shfl_xor(a2, 32, 64);
    a3 += __shfl_xor(a3, 16, 64); a3 += __shfl_xor(a3, 32, 64);
    a4 += __shfl_xor(a4, 16, 64); a4 += __shfl_xor(a4, 32, 64);
    a5 += __shfl_xor(a5, 16, 64); a5 += __shfl_xor(a5, 32, 64);
    a6 += __shfl_xor(a6, 16, 64); a6 += __shfl_xor(a6, 32, 64);
    a7 += __shfl_xor(a7, 16, 64); a7 += __shfl_xor(a7, 32, 64);
    wsum += __shfl_xor(wsum, 16, 64); wsum += __shfl_xor(wsum, 32, 64);
    if (q == 0) {
        const float inv = 1.f / ((wsum == 0.f) ? 1.f : wsum);
        float* o = out + (size_t)row * DIM + 8 * l;
        *(float4*)o       = make_float4(a0 * inv, a1 * inv, a2 * inv, a3 * inv);
        *(float4*)(o + 4) = make_float4(a4 * inv, a5 * inv, a6 * inv, a7 * inv);
    }
}

extern "C" void kernel_launch(void* const* d_in, const int* in_sizes, int n_in,
                              void* d_out, int out_size, void* d_ws, size_t ws_size,
                              hipStream_t stream) {
    const float* fa    = (const float*)d_in[0];
    const float* fb    = (const float*)d_in[1];
    const void*  edges = d_in[2];
    const float* W     = (const float*)d_in[3];
    const float* bias  = (const float*)d_in[4];
    const float* avec  = (const float*)d_in[5];
    float* out = (float*)d_out;
    char* ws = (char*)d_ws;
    short* nebf  = (short*)(ws + WS_NEBF);
    short* wbf   = (short*)(ws + WS_WBF);
    float* s_a   = (float*)(ws + WS_SA);
    float* s_b   = (float*)(ws + WS_SB);
    int*   cnt   = (int*)(ws + WS_CNT);
    int*   flags = (int*)(ws + WS_FLAG);
    int2*  ovf   = (int2*)(ws + WS_OVF);
    int*   bucket= (int*)(ws + WS_PAIRS);

    // zero cnt[NA] + flags[16] in one memset (flags[1] is the overflow counter)
    (void)hipMemsetAsync(ws + WS_CNT, 0, (size_t)NA * sizeof(int) + 64, stream);
    k_prep<<<1 + (DIM * DIM + 255) / 256, 256, 0, stream>>>((const int*)edges, flags, W, wbf);
    k_fused<<<NEWEMB_BLOCKS + SCAT_BLOCKS + SA_BLOCKS, 256, 0, stream>>>(
        fb, wbf, bias, avec, nebf, s_b,
        edges, flags, cnt, bucket, ovf, &flags[1],
        fa, s_a);
    k_rowagg<<<(NA + 3) / 4, 256, 0, stream>>>(cnt, bucket, s_a, s_b,
                                               (const unsigned*)nebf, ovf, flags, out);
}

// Round 8
// 360.387 us; speedup vs baseline: 1.0296x; 1.0296x over previous
//
#include <hip/hip_runtime.h>
#include <math.h>

#define NA 100000
#define NB 100000
#define DIM 128
#define NEDGE 1600000
#define ALPHA 0.1f
#define BCAP 32        // P(Poisson(16) > 32) ~ 1.5e-4 -> ~25 overflow edges, handled exactly
#define OVF_CAP 65536

// ---- workspace layout (bytes, all 64-aligned) ----
// Common prefix; bucket at WS_PAIRS is either int2[NA*32] (path A, 25.6MB) or
// int[NA*32] (path B, 12.8MB). Path A total 52,957,120 bytes -> only used when
// ws_size proves it fits (R0 lesson: never write past the proven envelope).
#define WS_NEBF   0          // 25,600,000  bf16 new_emb[NB*DIM]
#define WS_WBF    25600000   //     32,768  bf16 W[DIM*DIM]
#define WS_SA     25632768   //    400,000  float s_a[NA]
#define WS_SB     26032768   //    400,000  float s_b[NB]
#define WS_CNT    26432768   //    400,000  int cnt[NA] (cursor; counts ALL edges of row)
#define WS_FLAG   26832768   //         64  int flags[16]: [0]=int64-layout, [1]=overflow counter
#define WS_OVF    26832832   //    524,288  int2 ovf[OVF_CAP] = (src,dst)
#define WS_PAIRS  27357120   // bucket array
#define WS_TOTAL_A (27357120 + (size_t)NA * BCAP * 8)   // 52,957,120
#define WS_TOTAL_B (27357120 + (size_t)NA * BCAP * 4)   // 40,157,120 (proven OK)

using bf16x8 = __attribute__((ext_vector_type(8))) short;
using f32x16 = __attribute__((ext_vector_type(16))) float;

__device__ inline short f2bf(float f) {   // RNE float->bf16
    union { float f; unsigned u; } v; v.f = f;
    const unsigned r = (v.u + 0x7FFFu + ((v.u >> 16) & 1u)) >> 16;
    return (short)r;
}

// block 0: edge-layout detect (int64 high words all zero?); blocks 1..64: W -> bf16
__global__ void k_prep(const int* __restrict__ edges32, int* __restrict__ flags,
                       const float* __restrict__ W, short* __restrict__ wbf) {
    if (blockIdx.x == 0) {
        __shared__ int any;
        if (threadIdx.x == 0) any = 0;
        __syncthreads();
        if (edges32[2 * threadIdx.x + 1] != 0) atomicOr(&any, 1);
        __syncthreads();
        if (threadIdx.x == 0) flags[0] = (any == 0) ? 1 : 0;
    } else {
        const int i = (blockIdx.x - 1) * 256 + threadIdx.x;
        if (i < DIM * DIM) wbf[i] = f2bf(W[i]);
    }
}

// new_emb(bf16) = fb @ W^T + b ; s_b = new_emb @ a_bot.  MFMA 32x32x16 bf16.  (proven R2 kernel)
__global__ __launch_bounds__(256) void k_newemb(
    const float* __restrict__ fb, const short* __restrict__ wbf,
    const float* __restrict__ bias, const float* __restrict__ avec,
    short* __restrict__ nebf, float* __restrict__ s_b)
{
    const int wv = threadIdx.x >> 6;
    const int lane = threadIdx.x & 63;
    const int tile = blockIdx.x * 4 + wv;
    const int row0 = tile * 32;
    if (row0 >= NB) return;
    const int l31 = lane & 31;
    const int h = lane >> 5;

    f32x16 acc[4];
    #pragma unroll
    for (int nt = 0; nt < 4; ++nt)
        #pragma unroll
        for (int r = 0; r < 16; ++r) acc[nt][r] = 0.f;

    const float* arow = fb + (size_t)(row0 + l31) * DIM;   // A: m = lane&31

    #pragma unroll 2
    for (int s = 0; s < 8; ++s) {
        const int k0 = s * 16 + h * 8;                     // A/B: k = 8*(lane>>5)+j
        const float4 a0 = *(const float4*)(arow + k0);
        const float4 a1 = *(const float4*)(arow + k0 + 4);
        bf16x8 af;
        af[0] = f2bf(a0.x); af[1] = f2bf(a0.y); af[2] = f2bf(a0.z); af[3] = f2bf(a0.w);
        af[4] = f2bf(a1.x); af[5] = f2bf(a1.y); af[6] = f2bf(a1.z); af[7] = f2bf(a1.w);
        #pragma unroll
        for (int nt = 0; nt < 4; ++nt) {
            const int n = nt * 32 + l31;                   // B[k][n] = W[n][k]
            const bf16x8 bf = *(const bf16x8*)(wbf + n * DIM + k0);
            acc[nt] = __builtin_amdgcn_mfma_f32_32x32x16_bf16(af, bf, acc[nt], 0, 0, 0);
        }
    }

    float ab[4], bs[4];
    #pragma unroll
    for (int nt = 0; nt < 4; ++nt) {
        ab[nt] = avec[DIM + nt * 32 + l31];   // a_bot
        bs[nt] = bias[nt * 32 + l31];
    }
    float sb[16];
    #pragma unroll
    for (int r = 0; r < 16; ++r) {
        const int row = row0 + (r & 3) + 8 * (r >> 2) + 4 * h;  // C/D row map
        float p = 0.f;
        #pragma unroll
        for (int nt = 0; nt < 4; ++nt) {
            const float v = acc[nt][r] + bs[nt];
            nebf[(size_t)row * DIM + nt * 32 + l31] = f2bf(v);
            p += v * ab[nt];
        }
        #pragma unroll
        for (int m = 16; m; m >>= 1) p += __shfl_xor(p, m, 64);  // reduce over lane&31
        sb[r] = p;
    }
    if (l31 == 0) {
        #pragma unroll
        for (int r = 0; r < 16; ++r)
            s_b[row0 + (r & 3) + 8 * (r >> 2) + 4 * h] = sb[r];
    }
}

// s_a = feature_a @ a_top : one wave per row  (proven R2 kernel)
__global__ __launch_bounds__(256) void k_sa(
    const float* __restrict__ fa, const float* __restrict__ avec,
    float* __restrict__ s_a)
{
    const int row = blockIdx.x * 4 + (threadIdx.x >> 6);
    if (row >= NA) return;
    const int lane = threadIdx.x & 63;
    const float2 v = *(const float2*)(fa + (size_t)row * DIM + 2 * lane);
    const float2 a = *(const float2*)(avec + 2 * lane);
    float p = v.x * a.x + v.y * a.y;
    #pragma unroll
    for (int m = 32; m; m >>= 1) p += __shfl_xor(p, m, 64);
    if (lane == 0) s_a[row] = p;
}

__device__ inline float edge_w(float sar, float sb) {
    const float sc = sar + sb;
    const float el = (sc > 0.f) ? sc : ALPHA * expm1f(sc);
    return expf(el);
}

// ---- PATH A: scatter with w computed here, 8B (dst,w) entries (R2 k_place's
// proven per-edge shape: 75us @1.35 TB/s vs 4B-entry scatter's 112us @0.86) ----
__global__ __launch_bounds__(256) void k_scatter_w(
    const void* __restrict__ edges, const int* __restrict__ flags,
    const float* __restrict__ s_a, const float* __restrict__ s_b,
    int* __restrict__ cnt, int2* __restrict__ bucket,
    int2* __restrict__ ovf, int* __restrict__ ovfcnt)
{
    const int e = blockIdx.x * 256 + threadIdx.x;
    if (e >= NEDGE) return;
    int src, dst;
    if (flags[0]) {
        const int4 v = ((const int4*)edges)[e];
        src = v.x; dst = v.z;
    } else {
        const int2 v = ((const int2*)edges)[e];
        src = v.x; dst = v.y;
    }
    const float w = edge_w(s_a[src], s_b[dst]);
    const int pos = atomicAdd(&cnt[src], 1);
    if (pos < BCAP) {
        bucket[(src << 5) + pos] = make_int2(dst, __float_as_int(w));
    } else {
        const int o = atomicAdd(ovfcnt, 1);
        if (o < OVF_CAP) ovf[o] = make_int2(src, dst);
    }
}

// ---- PATH B: 4B dst-only entries (R5 proven, 40.16MB) ----
__global__ __launch_bounds__(256) void k_scatter(
    const void* __restrict__ edges, const int* __restrict__ flags,
    int* __restrict__ cnt, int* __restrict__ bucket,
    int2* __restrict__ ovf, int* __restrict__ ovfcnt)
{
    const int e = blockIdx.x * 256 + threadIdx.x;
    if (e >= NEDGE) return;
    int src, dst;
    if (flags[0]) {
        const int4 v = ((const int4*)edges)[e];
        src = v.x; dst = v.z;
    } else {
        const int2 v = ((const int2*)edges)[e];
        src = v.x; dst = v.y;
    }
    const int pos = atomicAdd(&cnt[src], 1);
    if (pos < BCAP) {
        bucket[(src << 5) + pos] = dst;
    } else {
        const int o = atomicAdd(ovfcnt, 1);
        if (o < OVF_CAP) ovf[o] = make_int2(src, dst);
    }
}

// one wave per src row, quarter-wave per edge: 16 lanes x uint4 = full 256B bf16 row,
// 4-deep MLP (16 gathers in flight per wave).
#define ACC8(u, wt)                                                             \
    a0 += (wt) * __uint_as_float((u).x << 16);                                  \
    a1 += (wt) * __uint_as_float((u).x & 0xFFFF0000u);                          \
    a2 += (wt) * __uint_as_float((u).y << 16);                                  \
    a3 += (wt) * __uint_as_float((u).y & 0xFFFF0000u);                          \
    a4 += (wt) * __uint_as_float((u).z << 16);                                  \
    a5 += (wt) * __uint_as_float((u).z & 0xFFFF0000u);                          \
    a6 += (wt) * __uint_as_float((u).w << 16);                                  \
    a7 += (wt) * __uint_as_float((u).w & 0xFFFF0000u);

#define ROWAGG_REDUCE_STORE                                                     \
    a0 += __shfl_xor(a0, 16, 64); a0 += __shfl_xor(a0, 32, 64);                 \
    a1 += __shfl_xor(a1, 16, 64); a1 += __shfl_xor(a1, 32, 64);                 \
    a2 += __shfl_xor(a2, 16, 64); a2 += __shfl_xor(a2, 32, 64);                 \
    a3 += __shfl_xor(a3, 16, 64); a3 += __shfl_xor(a3, 32, 64);                 \
    a4 += __shfl_xor(a4, 16, 64); a4 += __shfl_xor(a4, 32, 64);                 \
    a5 += __shfl_xor(a5, 16, 64); a5 += __shfl_xor(a5, 32, 64);                 \
    a6 += __shfl_xor(a6, 16, 64); a6 += __shfl_xor(a6, 32, 64);                 \
    a7 += __shfl_xor(a7, 16, 64); a7 += __shfl_xor(a7, 32, 64);                 \
    wsum += __shfl_xor(wsum, 16, 64); wsum += __shfl_xor(wsum, 32, 64);         \
    if (q == 0) {                                                               \
        const float inv = 1.f / ((wsum == 0.f) ? 1.f : wsum);                   \
        float* o = out + (size_t)row * DIM + 8 * l;                             \
        *(float4*)o       = make_float4(a0 * inv, a1 * inv, a2 * inv, a3 * inv);\
        *(float4*)(o + 4) = make_float4(a4 * inv, a5 * inv, a6 * inv, a7 * inv);\
    }

// PATH A rowagg: w read from bucket (no s_b gather / expf per edge)
__global__ __launch_bounds__(256) void k_rowagg_w(
    const int* __restrict__ cnt, const int2* __restrict__ bucket_all,
    const float* __restrict__ s_a, const float* __restrict__ s_b,
    const unsigned* __restrict__ nebf, const int2* __restrict__ ovf,
    const int* __restrict__ flags, float* __restrict__ out)
{
    const int row = blockIdx.x * 4 + (threadIdx.x >> 6);
    if (row >= NA) return;
    const int lane = threadIdx.x & 63;
    const int l = lane & 15;
    const int q = lane >> 4;
    const int c = cnt[row];
    const int cb = (c > BCAP) ? BCAP : c;
    const int2* bucket = bucket_all + (row << 5);

    float a0 = 0.f, a1 = 0.f, a2 = 0.f, a3 = 0.f;
    float a4 = 0.f, a5 = 0.f, a6 = 0.f, a7 = 0.f, wsum = 0.f;
    int i = q;
    for (; i + 12 < cb; i += 16) {
        const int2 p0 = bucket[i];
        const int2 p1 = bucket[i + 4];
        const int2 p2 = bucket[i + 8];
        const int2 p3 = bucket[i + 12];
        const uint4 u0 = *(const uint4*)(nebf + (size_t)p0.x * (DIM / 2) + 4 * l);
        const uint4 u1 = *(const uint4*)(nebf + (size_t)p1.x * (DIM / 2) + 4 * l);
        const uint4 u2 = *(const uint4*)(nebf + (size_t)p2.x * (DIM / 2) + 4 * l);
        const uint4 u3 = *(const uint4*)(nebf + (size_t)p3.x * (DIM / 2) + 4 * l);
        const float w0 = __int_as_float(p0.y);
        const float w1 = __int_as_float(p1.y);
        const float w2 = __int_as_float(p2.y);
        const float w3 = __int_as_float(p3.y);
        ACC8(u0, w0) ACC8(u1, w1) ACC8(u2, w2) ACC8(u3, w3)
        wsum += (w0 + w1) + (w2 + w3);
    }
    for (; i + 4 < cb; i += 8) {
        const int2 p0 = bucket[i];
        const int2 p1 = bucket[i + 4];
        const uint4 u0 = *(const uint4*)(nebf + (size_t)p0.x * (DIM / 2) + 4 * l);
        const uint4 u1 = *(const uint4*)(nebf + (size_t)p1.x * (DIM / 2) + 4 * l);
        const float w0 = __int_as_float(p0.y);
        const float w1 = __int_as_float(p1.y);
        ACC8(u0, w0) ACC8(u1, w1)
        wsum += w0 + w1;
    }
    for (; i < cb; i += 4) {
        const int2 p = bucket[i];
        const uint4 u = *(const uint4*)(nebf + (size_t)p.x * (DIM / 2) + 4 * l);
        const float wv = __int_as_float(p.y);
        ACC8(u, wv)
        wsum += wv;
    }
    // exact overflow fold-in (~25 entries; w recomputed, negligible)
    int novf = flags[1];
    novf = (novf > OVF_CAP) ? OVF_CAP : novf;
    const float sar = s_a[row];
    for (int j = q; j < novf; j += 4) {
        const int2 pe = ovf[j];
        if (pe.x == row) {
            const uint4 u = *(const uint4*)(nebf + (size_t)pe.y * (DIM / 2) + 4 * l);
            const float wv = edge_w(sar, s_b[pe.y]);
            ACC8(u, wv)
            wsum += wv;
        }
    }
    ROWAGG_REDUCE_STORE
}

// PATH B rowagg: w recomputed from s_a + s_b (R5/R7 proven)
__global__ __launch_bounds__(256) void k_rowagg(
    const int* __restrict__ cnt, const int* __restrict__ bucket_all,
    const float* __restrict__ s_a, const float* __restrict__ s_b,
    const unsigned* __restrict__ nebf, const int2* __restrict__ ovf,
    const int* __restrict__ flags, float* __restrict__ out)
{
    const int row = blockIdx.x * 4 + (threadIdx.x >> 6);
    if (row >= NA) return;
    const int lane = threadIdx.x & 63;
    const int l = lane & 15;
    const int q = lane >> 4;
    const int c = cnt[row];
    const int cb = (c > BCAP) ? BCAP : c;
    const int* bucket = bucket_all + (row << 5);
    const float sar = s_a[row];

    float a0 = 0.f, a1 = 0.f, a2 = 0.f, a3 = 0.f;
    float a4 = 0.f, a5 = 0.f, a6 = 0.f, a7 = 0.f, wsum = 0.f;
    int i = q;
    for (; i + 12 < cb; i += 16) {
        const int d0 = bucket[i];
        const int d1 = bucket[i + 4];
        const int d2 = bucket[i + 8];
        const int d3 = bucket[i + 12];
        const uint4 u0 = *(const uint4*)(nebf + (size_t)d0 * (DIM / 2) + 4 * l);
        const uint4 u1 = *(const uint4*)(nebf + (size_t)d1 * (DIM / 2) + 4 * l);
        const uint4 u2 = *(const uint4*)(nebf + (size_t)d2 * (DIM / 2) + 4 * l);
        const uint4 u3 = *(const uint4*)(nebf + (size_t)d3 * (DIM / 2) + 4 * l);
        const float w0 = edge_w(sar, s_b[d0]);
        const float w1 = edge_w(sar, s_b[d1]);
        const float w2 = edge_w(sar, s_b[d2]);
        const float w3 = edge_w(sar, s_b[d3]);
        ACC8(u0, w0) ACC8(u1, w1) ACC8(u2, w2) ACC8(u3, w3)
        wsum += (w0 + w1) + (w2 + w3);
    }
    for (; i + 4 < cb; i += 8) {
        const int d0 = bucket[i];
        const int d1 = bucket[i + 4];
        const uint4 u0 = *(const uint4*)(nebf + (size_t)d0 * (DIM / 2) + 4 * l);
        const uint4 u1 = *(const uint4*)(nebf + (size_t)d1 * (DIM / 2) + 4 * l);
        const float w0 = edge_w(sar, s_b[d0]);
        const float w1 = edge_w(sar, s_b[d1]);
        ACC8(u0, w0) ACC8(u1, w1)
        wsum += w0 + w1;
    }
    for (; i < cb; i += 4) {
        const int d = bucket[i];
        const uint4 u = *(const uint4*)(nebf + (size_t)d * (DIM / 2) + 4 * l);
        const float wv = edge_w(sar, s_b[d]);
        ACC8(u, wv)
        wsum += wv;
    }
    int novf = flags[1];
    novf = (novf > OVF_CAP) ? OVF_CAP : novf;
    for (int j = q; j < novf; j += 4) {
        const int2 pe = ovf[j];
        if (pe.x == row) {
            const uint4 u = *(const uint4*)(nebf + (size_t)pe.y * (DIM / 2) + 4 * l);
            const float wv = edge_w(sar, s_b[pe.y]);
            ACC8(u, wv)
            wsum += wv;
        }
    }
    ROWAGG_REDUCE_STORE
}

extern "C" void kernel_launch(void* const* d_in, const int* in_sizes, int n_in,
                              void* d_out, int out_size, void* d_ws, size_t ws_size,
                              hipStream_t stream) {
    const float* fa    = (const float*)d_in[0];
    const float* fb    = (const float*)d_in[1];
    const void*  edges = d_in[2];
    const float* W     = (const float*)d_in[3];
    const float* bias  = (const float*)d_in[4];
    const float* avec  = (const float*)d_in[5];
    float* out = (float*)d_out;
    char* ws = (char*)d_ws;
    short* nebf  = (short*)(ws + WS_NEBF);
    short* wbf   = (short*)(ws + WS_WBF);
    float* s_a   = (float*)(ws + WS_SA);
    float* s_b   = (float*)(ws + WS_SB);
    int*   cnt   = (int*)(ws + WS_CNT);
    int*   flags = (int*)(ws + WS_FLAG);
    int2*  ovf   = (int2*)(ws + WS_OVF);

    // ws_size is launch-invariant -> same kernel sequence every capture/replay
    const bool wide = (ws_size >= WS_TOTAL_A);

    // zero cnt[NA] + flags[16] in one memset (flags[1] is the overflow counter)
    (void)hipMemsetAsync(ws + WS_CNT, 0, (size_t)NA * sizeof(int) + 64, stream);
    k_prep<<<1 + (DIM * DIM + 255) / 256, 256, 0, stream>>>((const int*)edges, flags, W, wbf);
    k_newemb<<<(NB / 32 + 3) / 4, 256, 0, stream>>>(fb, wbf, bias, avec, nebf, s_b);
    k_sa<<<(NA + 3) / 4, 256, 0, stream>>>(fa, avec, s_a);
    if (wide) {
        int2* bucket2 = (int2*)(ws + WS_PAIRS);
        k_scatter_w<<<(NEDGE + 255) / 256, 256, 0, stream>>>(
            edges, flags, s_a, s_b, cnt, bucket2, ovf, &flags[1]);
        k_rowagg_w<<<(NA + 3) / 4, 256, 0, stream>>>(
            cnt, bucket2, s_a, s_b, (const unsigned*)nebf, ovf, flags, out);
    } else {
        int* bucket = (int*)(ws + WS_PAIRS);
        k_scatter<<<(NEDGE + 255) / 256, 256, 0, stream>>>(
            edges, flags, cnt, bucket, ovf, &flags[1]);
        k_rowagg<<<(NA + 3) / 4, 256, 0, stream>>>(
            cnt, bucket, s_a, s_b, (const unsigned*)nebf, ovf, flags, out);
    }
}